// Round 3
// baseline (844.519 us; speedup 1.0000x reference)
//
#include <hip/hip_runtime.h>
#include <hip/hip_cooperative_groups.h>

namespace cg = cooperative_groups;

// Text2SemanticDecoder decode step. Primary path: one persistent cooperative
// kernel (512 blocks x 256 thr, 24.6 KB LDS -> >=2 blocks/CU under any LDS
// accounting). Fallback path (if occupancy gate fails): round-1 multi-kernel
// sequence, known correct.

#define DEV __device__ __forceinline__

static constexpr int LNUM = 24;
static constexpr int B = 4;
static constexpr int H = 16;
static constexpr int D = 512;
static constexpr int S = 4096;
static constexpr int FF = 2048;
static constexpr int HD = 32;
static constexpr int NCH = 9;   // fallback path chunking
static constexpr float EPS = 1e-5f;
static constexpr float SCALE = 0.17677669529663687f;  // 1/sqrt(32)

DEV float waveReduceSum(float v) {
#pragma unroll
    for (int o = 32; o > 0; o >>= 1) v += __shfl_xor(v, o);
    return v;
}
DEV float waveReduceMax(float v) {
#pragma unroll
    for (int o = 32; o > 0; o >>= 1) v = fmaxf(v, __shfl_xor(v, o));
    return v;
}
DEV float blockReduceSum(float v, volatile float* red) {
    v = waveReduceSum(v);
    __syncthreads();
    if ((threadIdx.x & 63) == 0) red[threadIdx.x >> 6] = v;
    __syncthreads();
    return red[0] + red[1] + red[2] + red[3];
}
DEV float blockReduceMax(float v, volatile float* red) {
    v = waveReduceMax(v);
    __syncthreads();
    if ((threadIdx.x & 63) == 0) red[threadIdx.x >> 6] = v;
    __syncthreads();
    return fmaxf(fmaxf(red[0], red[1]), fmaxf(red[2], red[3]));
}

struct Params {
    const float *x, *kc, *vc;
    const float *qkvw, *qkvb, *outw, *outb, *w1, *b1, *w2, *b2;
    const float *nw1, *nb1, *nw2, *nb2;
    const int* posp;
    float *qkvbuf, *part, *t1, *m1, *sbuf, *out;
};

// ============================ cooperative mega-kernel ============================
// LDS (floats), max 6160 = 24.6 KB:
//  phase1/3/4: [0..2047] staged hidden (4x512); phase3: [2048..2175] mh/sh,
//  [2176..4223] combined attn. phase5: [0..4095] m1 half (4x1024),
//  [4096..6143] t1 raw. [6152..6155] block-reduce scratch.
__global__ __launch_bounds__(256, 2) void mega(Params p) {
    cg::grid_group grid = cg::this_grid();
    const int blk = blockIdx.x;   // 0..511
    const int tid = threadIdx.x;  // 0..255
    const int w = tid >> 6;       // wave 0..3 (doubles as batch index)
    const int lane = tid & 63;
    const int pos = p.posp[0];

    __shared__ float SM[6160];
    float* red = SM + 6152;

    for (int l = 0; l < LNUM; ++l) {
        const float* hsrc = (l == 0) ? p.x : p.sbuf;
        const bool aln = (l > 0);
        const float* pnw = p.nw2 + (aln ? (size_t)(l - 1) * 512 : 0);
        const float* pnb = p.nb2 + (aln ? (size_t)(l - 1) * 512 : 0);
        const float* qwL = p.qkvw + (size_t)l * 1536 * 512;
        const float* qbL = p.qkvb + (size_t)l * 1536;
        const float* kcL = p.kc + (size_t)l * 8388608;
        const float* vcL = p.vc + (size_t)l * 8388608;
        const float* owL = p.outw + (size_t)l * 512 * 512;
        const float* obL = p.outb + (size_t)l * 512;
        const float* w1L = p.w1 + (size_t)l * 2048 * 512;
        const float* b1L = p.b1 + (size_t)l * 2048;
        const float* w2L = p.w2 + (size_t)l * 512 * 2048;
        const float* b2L = p.b2 + (size_t)l * 512;
        const float* n1w = p.nw1 + (size_t)l * 512;
        const float* n1b = p.nb1 + (size_t)l * 512;

        // ===== Phase 1: stage h (+LN2) in LDS; qkv GEMV, wave per row, all b =====
        {
            const float4* s4 = (const float4*)hsrc;
            float4* m4 = (float4*)SM;
            m4[tid] = s4[tid];
            m4[tid + 256] = s4[tid + 256];
            __syncthreads();
            float4* h4 = (float4*)(SM + (w << 9));
            float4 aa = h4[lane], bb = h4[lane + 64];
            float s = aa.x + aa.y + aa.z + aa.w + bb.x + bb.y + bb.z + bb.w;
            float s2 = aa.x * aa.x + aa.y * aa.y + aa.z * aa.z + aa.w * aa.w
                     + bb.x * bb.x + bb.y * bb.y + bb.z * bb.z + bb.w * bb.w;
            s = waveReduceSum(s);
            s2 = waveReduceSum(s2);
            float mean = s * (1.f / 512.f);
            float rs = rsqrtf(s2 * (1.f / 512.f) - mean * mean + EPS);
            if (aln) {
                const float4* gw4 = (const float4*)pnw;
                const float4* gb4 = (const float4*)pnb;
                float4 gw = gw4[lane], gb = gb4[lane];
                aa.x = (aa.x - mean) * rs * gw.x + gb.x;
                aa.y = (aa.y - mean) * rs * gw.y + gb.y;
                aa.z = (aa.z - mean) * rs * gw.z + gb.z;
                aa.w = (aa.w - mean) * rs * gw.w + gb.w;
                h4[lane] = aa;
                gw = gw4[lane + 64]; gb = gb4[lane + 64];
                bb.x = (bb.x - mean) * rs * gw.x + gb.x;
                bb.y = (bb.y - mean) * rs * gw.y + gb.y;
                bb.z = (bb.z - mean) * rs * gw.z + gb.z;
                bb.w = (bb.w - mean) * rs * gw.w + gb.w;
                h4[lane + 64] = bb;
            }
            __syncthreads();
            const int r = (blk << 2) + w;
            if (r < 1536) {
                const float4* wr4 = (const float4*)(qwL + (size_t)r * 512);
                float4 wA = wr4[lane], wB = wr4[lane + 64];
                float acc[4];
#pragma unroll
                for (int b = 0; b < 4; ++b) {
                    const float4* hb4 = (const float4*)(SM + (b << 9));
                    float4 hA = hb4[lane], hB = hb4[lane + 64];
                    float a = wA.x * hA.x + wA.y * hA.y + wA.z * hA.z + wA.w * hA.w
                            + wB.x * hB.x + wB.y * hB.y + wB.z * hB.z + wB.w * hB.w;
                    acc[b] = waveReduceSum(a);
                }
                if (lane == 0) {
                    float bias = qbL[r];
                    float sc = (r < 512) ? SCALE : 1.f;
#pragma unroll
                    for (int b = 0; b < 4; ++b)
                        p.qkvbuf[b * 1536 + r] = (acc[b] + bias) * sc;
                }
            }
        }
        grid.sync();

        // ===== Phase 2: attention partials; block = (bh, chunk of 256 pos) =====
        {
            const int c = blk & 7, bh = blk >> 3;
            const int b = bh >> 4, h = bh & 15;
            float* qs = SM;        // 32
            float* es = SM + 32;   // 256
            float* op = SM + 288;  // 8*33
            float* sn = SM + 560;  // 1
            if (tid < 32) qs[tid] = p.qkvbuf[b * 1536 + h * 32 + tid];
            __syncthreads();
            const int pp = (c << 8) + tid;
            const bool act = pp < pos;
            const float4* kp = (const float4*)(kcL + ((size_t)bh * 4096 + pp) * 32);
            float sc = 0.f;
#pragma unroll
            for (int i = 0; i < 8; ++i) {
                float4 kv = kp[i];
                sc += qs[4 * i] * kv.x + qs[4 * i + 1] * kv.y
                    + qs[4 * i + 2] * kv.z + qs[4 * i + 3] * kv.w;
            }
            float score = act ? sc : -1e30f;
            float smax = score;
            float snew = 0.f;
            if (c == 7 && tid == 0) {
                const float* kn = p.qkvbuf + b * 1536 + 512 + h * 32;
                for (int j = 0; j < 32; ++j) snew += qs[j] * kn[j];
                smax = fmaxf(smax, snew);
            }
            float m = blockReduceMax(smax, red);
            if (tid == 0) sn[0] = (c == 7) ? expf(snew - m) : 0.f;
            float e = act ? expf(score - m) : 0.f;
            es[tid] = e;
            float lsum = blockReduceSum(e, red) + sn[0];
            const int d = tid & 31, g = tid >> 5;
            float acc = 0.f;
            const float* vp = vcL + ((size_t)bh * 4096 + (c << 8) + (g << 5)) * 32 + d;
#pragma unroll 8
            for (int i = 0; i < 32; ++i) acc += es[(g << 5) + i] * vp[(size_t)i * 32];
            if (g == 0) acc += sn[0] * p.qkvbuf[b * 1536 + 1024 + h * 32 + d];
            op[g * 33 + d] = acc;
            __syncthreads();
            if (tid < 32) {
                float o = 0.f;
#pragma unroll
                for (int gg = 0; gg < 8; ++gg) o += op[gg * 33 + tid];
                float* pt = p.part + (size_t)((bh << 3) + c) * 34;
                pt[2 + tid] = o;
                if (tid == 0) { pt[0] = m; pt[1] = lsum; }
            }
        }
        grid.sync();

        // ===== Phase 3: combine chunks + out-proj + residual -> t1 raw =====
        {
            const float4* s4 = (const float4*)hsrc;
            float4* m4 = (float4*)SM;
            m4[tid] = s4[tid];
            m4[tid + 256] = s4[tid + 256];
            __syncthreads();
            float4* h4 = (float4*)(SM + (w << 9));
            float4 aa = h4[lane], bb = h4[lane + 64];
            float s = aa.x + aa.y + aa.z + aa.w + bb.x + bb.y + bb.z + bb.w;
            float s2 = aa.x * aa.x + aa.y * aa.y + aa.z * aa.z + aa.w * aa.w
                     + bb.x * bb.x + bb.y * bb.y + bb.z * bb.z + bb.w * bb.w;
            s = waveReduceSum(s);
            s2 = waveReduceSum(s2);
            float mean = s * (1.f / 512.f);
            float rs = rsqrtf(s2 * (1.f / 512.f) - mean * mean + EPS);
            if (tid < 64) {
                const float* pt = p.part + (size_t)(tid << 3) * 34;
                float mh = -1e30f;
#pragma unroll
                for (int cc = 0; cc < 8; ++cc) mh = fmaxf(mh, pt[cc * 34]);
                float ssum = 0.f;
#pragma unroll
                for (int cc = 0; cc < 8; ++cc) ssum += pt[cc * 34 + 1] * expf(pt[cc * 34] - mh);
                SM[2048 + tid] = mh;
                SM[2112 + tid] = ssum;
            }
            __syncthreads();
#pragma unroll
            for (int k = 0; k < 8; ++k) {
                int idx = tid + (k << 8);
                int b = idx >> 9, e = idx & 511, hh = e >> 5, dd = e & 31;
                int bh = (b << 4) + hh;
                const float* pt = p.part + (size_t)(bh << 3) * 34;
                float mh = SM[2048 + bh];
                float inv = 1.f / SM[2112 + bh];
                float o = 0.f;
#pragma unroll
                for (int cc = 0; cc < 8; ++cc) o += pt[cc * 34 + 2 + dd] * expf(pt[cc * 34] - mh);
                SM[2176 + idx] = o * inv;
            }
            __syncthreads();
            const int dd = blk;  // output dim 0..511
            const float4* wr4 = (const float4*)(owL + (size_t)dd * 512);
            float4 wA = wr4[lane], wB = wr4[lane + 64];
            const float4* a4 = (const float4*)(SM + 2176 + (w << 9));
            float4 hA = a4[lane], hB = a4[lane + 64];
            float acc = wA.x * hA.x + wA.y * hA.y + wA.z * hA.z + wA.w * hA.w
                      + wB.x * hB.x + wB.y * hB.y + wB.z * hB.z + wB.w * hB.w;
            acc = waveReduceSum(acc);
            if (lane == 0) {
                float hv = SM[(w << 9) + dd];
                if (aln) hv = (hv - mean) * rs * pnw[dd] + pnb[dd];
                p.t1[(w << 9) + dd] = hv + acc + obL[dd];
            }
        }
        grid.sync();

        // ===== Phase 4: LN1(t1) in LDS; mlp1 GEMV, wave per FF row, all b =====
        {
            const float4* s4 = (const float4*)p.t1;
            float4* m4 = (float4*)SM;
            m4[tid] = s4[tid];
            m4[tid + 256] = s4[tid + 256];
            __syncthreads();
            float4* h4 = (float4*)(SM + (w << 9));
            float4 aa = h4[lane], bb = h4[lane + 64];
            float s = aa.x + aa.y + aa.z + aa.w + bb.x + bb.y + bb.z + bb.w;
            float s2 = aa.x * aa.x + aa.y * aa.y + aa.z * aa.z + aa.w * aa.w
                     + bb.x * bb.x + bb.y * bb.y + bb.z * bb.z + bb.w * bb.w;
            s = waveReduceSum(s);
            s2 = waveReduceSum(s2);
            float mean = s * (1.f / 512.f);
            float rs = rsqrtf(s2 * (1.f / 512.f) - mean * mean + EPS);
            {
                const float4* gw4 = (const float4*)n1w;
                const float4* gb4 = (const float4*)n1b;
                float4 gw = gw4[lane], gb = gb4[lane];
                aa.x = (aa.x - mean) * rs * gw.x + gb.x;
                aa.y = (aa.y - mean) * rs * gw.y + gb.y;
                aa.z = (aa.z - mean) * rs * gw.z + gb.z;
                aa.w = (aa.w - mean) * rs * gw.w + gb.w;
                h4[lane] = aa;
                gw = gw4[lane + 64]; gb = gb4[lane + 64];
                bb.x = (bb.x - mean) * rs * gw.x + gb.x;
                bb.y = (bb.y - mean) * rs * gw.y + gb.y;
                bb.z = (bb.z - mean) * rs * gw.z + gb.z;
                bb.w = (bb.w - mean) * rs * gw.w + gb.w;
                h4[lane + 64] = bb;
            }
            __syncthreads();
            const int r = (blk << 2) + w;  // 0..2047
            const float4* wr4 = (const float4*)(w1L + (size_t)r * 512);
            float4 wA = wr4[lane], wB = wr4[lane + 64];
            float acc[4];
#pragma unroll
            for (int b = 0; b < 4; ++b) {
                const float4* hb4 = (const float4*)(SM + (b << 9));
                float4 hA = hb4[lane], hB = hb4[lane + 64];
                float a = wA.x * hA.x + wA.y * hA.y + wA.z * hA.z + wA.w * hA.w
                        + wB.x * hB.x + wB.y * hB.y + wB.z * hB.z + wB.w * hB.w;
                acc[b] = waveReduceSum(a);
            }
            if (lane == 0) {
                float bv = b1L[r];
#pragma unroll
                for (int b = 0; b < 4; ++b)
                    p.m1[(b << 11) + r] = fmaxf(acc[b] + bv, 0.f);
            }
        }
        grid.sync();

        // ===== Phase 5: mlp2 GEMV (two k-halves) + LN1(t1) residual -> sbuf =====
        {
            const float4* t4 = (const float4*)p.t1;
            float4* tB = (float4*)(SM + 4096);
            tB[tid] = t4[tid];
            tB[tid + 256] = t4[tid + 256];
            __syncthreads();
            const float4* h4 = (const float4*)(SM + 4096 + (w << 9));
            float4 aa = h4[lane], bb = h4[lane + 64];
            float s = aa.x + aa.y + aa.z + aa.w + bb.x + bb.y + bb.z + bb.w;
            float s2 = aa.x * aa.x + aa.y * aa.y + aa.z * aa.z + aa.w * aa.w
                     + bb.x * bb.x + bb.y * bb.y + bb.z * bb.z + bb.w * bb.w;
            s = waveReduceSum(s);
            s2 = waveReduceSum(s2);
            float mean = s * (1.f / 512.f);
            float rs = rsqrtf(s2 * (1.f / 512.f) - mean * mean + EPS);
            const int dd = blk;  // output dim 0..511
            const float4* wr4 = (const float4*)(w2L + (size_t)dd * 2048);
            float acc = 0.f;
#pragma unroll
            for (int half = 0; half < 2; ++half) {
                __syncthreads();  // protect previous-half reads before overwrite
#pragma unroll
                for (int i = 0; i < 4; ++i) {
                    int idx = tid + (i << 8);   // 0..1023 float4s
                    int b = idx >> 8;           // batch
                    int f = idx & 255;          // float4 within this half
                    ((float4*)SM)[idx] =
                        ((const float4*)(p.m1 + (b << 11) + (half << 10)))[f];
                }
                __syncthreads();
                const float4* mb4 = (const float4*)SM + (w << 8);
#pragma unroll
                for (int i = 0; i < 4; ++i) {
                    float4 q = wr4[(half << 8) + (i << 6) + lane];
                    float4 mm = mb4[(i << 6) + lane];
                    acc += q.x * mm.x + q.y * mm.y + q.z * mm.z + q.w * mm.w;
                }
            }
            acc = waveReduceSum(acc);
            if (lane == 0) {
                float tv = SM[4096 + (w << 9) + dd];
                float hv = (tv - mean) * rs * n1w[dd] + n1b[dd];
                p.sbuf[(w << 9) + dd] = hv + acc + b2L[dd];
            }
        }
        grid.sync();
    }

    // ===== Final LN2 (layer 23 params) -> d_out =====
    if (blk < 4) {
        const int b = blk;
        const float* nw = p.nw2 + 23 * 512;
        const float* nb = p.nb2 + 23 * 512;
        float a0 = p.sbuf[(b << 9) + tid];
        float a1 = p.sbuf[(b << 9) + 256 + tid];
        float s = blockReduceSum(a0 + a1, red);
        float s2 = blockReduceSum(a0 * a0 + a1 * a1, red);
        float mean = s * (1.f / 512.f);
        float rs = rsqrtf(s2 * (1.f / 512.f) - mean * mean + EPS);
        p.out[(b << 9) + tid] = (a0 - mean) * rs * nw[tid] + nb[tid];
        p.out[(b << 9) + 256 + tid] = (a1 - mean) * rs * nw[tid + 256] + nb[tid + 256];
    }
}

// ============================ fallback kernels (round-1, known-correct) ==========
__global__ __launch_bounds__(256) void k_qkv(
    const float* __restrict__ hsrc, int apply_ln,
    const float* __restrict__ nw, const float* __restrict__ nb,
    const float* __restrict__ w, const float* __restrict__ bias,
    float* __restrict__ qkv)
{
    const int lane = threadIdx.x & 63;
    const int wid = (blockIdx.x << 2) + (threadIdx.x >> 6);
    const int b = wid / 1536;
    const int r = wid - b * 1536;
    const float* hb = hsrc + (b << 9);
    const int k0 = lane << 3;
    float4 h0 = *(const float4*)(hb + k0);
    float4 h1 = *(const float4*)(hb + k0 + 4);
    float hv[8] = {h0.x, h0.y, h0.z, h0.w, h1.x, h1.y, h1.z, h1.w};
    if (apply_ln) {
        float s = 0.f, s2 = 0.f;
#pragma unroll
        for (int j = 0; j < 8; ++j) { s += hv[j]; s2 += hv[j] * hv[j]; }
        s = waveReduceSum(s);
        s2 = waveReduceSum(s2);
        float mean = s * (1.f / 512.f);
        float rs = rsqrtf(s2 * (1.f / 512.f) - mean * mean + EPS);
        float4 nw0 = *(const float4*)(nw + k0);
        float4 nw1 = *(const float4*)(nw + k0 + 4);
        float4 nb0 = *(const float4*)(nb + k0);
        float4 nb1 = *(const float4*)(nb + k0 + 4);
        float nwv[8] = {nw0.x, nw0.y, nw0.z, nw0.w, nw1.x, nw1.y, nw1.z, nw1.w};
        float nbv[8] = {nb0.x, nb0.y, nb0.z, nb0.w, nb1.x, nb1.y, nb1.z, nb1.w};
#pragma unroll
        for (int j = 0; j < 8; ++j) hv[j] = (hv[j] - mean) * rs * nwv[j] + nbv[j];
    }
    const float* wr = w + (size_t)r * 512 + k0;
    float4 w0 = *(const float4*)(wr);
    float4 w1 = *(const float4*)(wr + 4);
    float acc = w0.x * hv[0] + w0.y * hv[1] + w0.z * hv[2] + w0.w * hv[3]
              + w1.x * hv[4] + w1.y * hv[5] + w1.z * hv[6] + w1.w * hv[7];
    acc = waveReduceSum(acc);
    if (lane == 0) {
        float v = acc + bias[r];
        if (r < 512) v *= SCALE;
        qkv[b * 1536 + r] = v;
    }
}

__global__ __launch_bounds__(256) void k_attn(
    const float* __restrict__ kc, const float* __restrict__ vc,
    const float* __restrict__ qkv, float* __restrict__ part,
    const int* __restrict__ posp)
{
    const int tid = threadIdx.x;
    const int c = blockIdx.x % NCH;
    const int bh = blockIdx.x / NCH;
    const int b = bh >> 4, h = bh & 15;
    const int pos = posp[0];
    __shared__ float qs[32];
    __shared__ float es[256];
    __shared__ float red[4];
    __shared__ float op[8][33];
    if (tid < 32) qs[tid] = qkv[b * 1536 + h * 32 + tid];
    __syncthreads();
    float score = -1e30f;
    bool act = false;
    if (c < 8) {
        int p = c * 256 + tid;
        act = (p < pos);
        const float4* kp = (const float4*)(kc + ((size_t)bh * S + p) * HD);
        float s = 0.f;
#pragma unroll
        for (int i = 0; i < 8; ++i) {
            float4 kv = kp[i];
            s += qs[4 * i] * kv.x + qs[4 * i + 1] * kv.y + qs[4 * i + 2] * kv.z + qs[4 * i + 3] * kv.w;
        }
        if (act) score = s;
    } else if (tid == 0) {
        act = true;
        const float* kp = qkv + b * 1536 + 512 + h * 32;
        float s = 0.f;
#pragma unroll
        for (int j = 0; j < 32; ++j) s += qs[j] * kp[j];
        score = s;
    }
    float m = blockReduceMax(score, red);
    float e = act ? expf(score - m) : 0.f;
    es[tid] = e;
    float l = blockReduceSum(e, red);
    const int d = tid & 31, g = tid >> 5;
    float acc = 0.f;
    if (c < 8) {
        const float* vp = vc + ((size_t)bh * S + c * 256 + g * 32) * HD + d;
#pragma unroll 8
        for (int i = 0; i < 32; ++i) acc += es[g * 32 + i] * vp[(size_t)i * HD];
    } else if (g == 0) {
        acc = es[0] * qkv[b * 1536 + 1024 + h * 32 + d];
    }
    op[g][d] = acc;
    __syncthreads();
    if (tid < 32) {
        float o = 0.f;
#pragma unroll
        for (int gg = 0; gg < 8; ++gg) o += op[gg][tid];
        float* pp = part + (size_t)(bh * NCH + c) * 34;
        pp[2 + tid] = o;
        if (tid == 0) { pp[0] = m; pp[1] = l; }
    }
}

__global__ __launch_bounds__(256) void k_outproj(
    const float* __restrict__ part,
    const float* __restrict__ ow, const float* __restrict__ ob,
    const float* __restrict__ hsrc, int apply_ln,
    const float* __restrict__ nw, const float* __restrict__ nb,
    float* __restrict__ t1)
{
    const int tid = threadIdx.x;
    const int b = blockIdx.x >> 5;
    const int oc = blockIdx.x & 31;
    __shared__ float attn_s[512];
    __shared__ float hln[512];
    __shared__ float mh[16], sh[16];
    __shared__ float red[4];
    if (tid < 16) {
        const float* pp = part + (size_t)(b * 16 + tid) * NCH * 34;
        float m = -1e30f;
        for (int c = 0; c < NCH; ++c) m = fmaxf(m, pp[c * 34]);
        float ss = 0.f;
        for (int c = 0; c < NCH; ++c) ss += pp[c * 34 + 1] * expf(pp[c * 34] - m);
        mh[tid] = m;
        sh[tid] = ss;
    }
    __syncthreads();
#pragma unroll
    for (int e = tid; e < 512; e += 256) {
        int h = e >> 5, d = e & 31;
        const float* pp = part + (size_t)(b * 16 + h) * NCH * 34;
        float o = 0.f;
        for (int c = 0; c < NCH; ++c) o += pp[c * 34 + 2 + d] * expf(pp[c * 34] - mh[h]);
        attn_s[e] = o / sh[h];
    }
    float a0 = hsrc[(b << 9) + tid], a1 = hsrc[(b << 9) + 256 + tid];
    if (apply_ln) {
        float s = blockReduceSum(a0 + a1, red);
        float s2 = blockReduceSum(a0 * a0 + a1 * a1, red);
        float mean = s * (1.f / 512.f);
        float rs = rsqrtf(s2 * (1.f / 512.f) - mean * mean + EPS);
        hln[tid] = (a0 - mean) * rs * nw[tid] + nb[tid];
        hln[tid + 256] = (a1 - mean) * rs * nw[tid + 256] + nb[tid + 256];
    } else {
        hln[tid] = a0;
        hln[tid + 256] = a1;
    }
    __syncthreads();
    const int w = tid >> 6, lane = tid & 63, k0 = lane << 3;
#pragma unroll
    for (int oi = 0; oi < 4; ++oi) {
        int dd = (oc << 4) + (w << 2) + oi;
        const float4* wp = (const float4*)(ow + (size_t)dd * 512 + k0);
        float4 w0 = wp[0], w1 = wp[1];
        float acc = w0.x * attn_s[k0] + w0.y * attn_s[k0 + 1] + w0.z * attn_s[k0 + 2] + w0.w * attn_s[k0 + 3]
                  + w1.x * attn_s[k0 + 4] + w1.y * attn_s[k0 + 5] + w1.z * attn_s[k0 + 6] + w1.w * attn_s[k0 + 7];
        acc = waveReduceSum(acc);
        if (lane == 0) t1[(b << 9) + dd] = hln[dd] + acc + ob[dd];
    }
}

__global__ __launch_bounds__(256) void k_mlp1(
    const float* __restrict__ t1,
    const float* __restrict__ nw, const float* __restrict__ nb,
    const float* __restrict__ w1, const float* __restrict__ b1,
    float* __restrict__ m1)
{
    const int tid = threadIdx.x;
    const int b = blockIdx.x >> 7;
    const int oc = blockIdx.x & 127;
    __shared__ float hln[512];
    __shared__ float red[4];
    float a0 = t1[(b << 9) + tid], a1 = t1[(b << 9) + 256 + tid];
    float s = blockReduceSum(a0 + a1, red);
    float s2 = blockReduceSum(a0 * a0 + a1 * a1, red);
    float mean = s * (1.f / 512.f);
    float rs = rsqrtf(s2 * (1.f / 512.f) - mean * mean + EPS);
    hln[tid] = (a0 - mean) * rs * nw[tid] + nb[tid];
    hln[tid + 256] = (a1 - mean) * rs * nw[tid + 256] + nb[tid + 256];
    __syncthreads();
    const int w = tid >> 6, lane = tid & 63, k0 = lane << 3;
#pragma unroll
    for (int oi = 0; oi < 4; ++oi) {
        int r = (oc << 4) + (w << 2) + oi;
        const float4* wp = (const float4*)(w1 + (size_t)r * 512 + k0);
        float4 w0 = wp[0], w1v = wp[1];
        float acc = w0.x * hln[k0] + w0.y * hln[k0 + 1] + w0.z * hln[k0 + 2] + w0.w * hln[k0 + 3]
                  + w1v.x * hln[k0 + 4] + w1v.y * hln[k0 + 5] + w1v.z * hln[k0 + 6] + w1v.w * hln[k0 + 7];
        acc = waveReduceSum(acc);
        if (lane == 0) m1[(b << 11) + r] = fmaxf(acc + b1[r], 0.f);
    }
}

__global__ __launch_bounds__(256) void k_mlp2(
    const float* __restrict__ m1, const float* __restrict__ t1,
    const float* __restrict__ nw, const float* __restrict__ nb,
    const float* __restrict__ w2, const float* __restrict__ b2,
    float* __restrict__ sout)
{
    const int tid = threadIdx.x;
    const int b = blockIdx.x >> 7;
    const int oc = blockIdx.x & 127;
    __shared__ float ms[2048];
    __shared__ float red[4];
#pragma unroll
    for (int i = 0; i < 8; ++i) ms[tid + (i << 8)] = m1[(b << 11) + tid + (i << 8)];
    float a0 = t1[(b << 9) + tid], a1 = t1[(b << 9) + 256 + tid];
    float s = blockReduceSum(a0 + a1, red);
    float s2 = blockReduceSum(a0 * a0 + a1 * a1, red);
    float mean = s * (1.f / 512.f);
    float rs = rsqrtf(s2 * (1.f / 512.f) - mean * mean + EPS);
    const int w = tid >> 6, lane = tid & 63;
    const int dd = (oc << 2) + w;
    const float4* wp = (const float4*)(w2 + (size_t)dd * 2048);
    float acc = 0.f;
#pragma unroll
    for (int i = 0; i < 8; ++i) {
        int idx = (i << 6) + lane;
        float4 q = wp[idx];
        int k = idx << 2;
        acc += q.x * ms[k] + q.y * ms[k + 1] + q.z * ms[k + 2] + q.w * ms[k + 3];
    }
    acc = waveReduceSum(acc);
    if (lane == 0) {
        float td = t1[(b << 9) + dd];
        float hd = (td - mean) * rs * nw[dd] + nb[dd];
        sout[(b << 9) + dd] = hd + acc + b2[dd];
    }
}

__global__ __launch_bounds__(256) void k_finalln(
    const float* __restrict__ sbuf,
    const float* __restrict__ nw, const float* __restrict__ nb,
    float* __restrict__ out)
{
    const int b = blockIdx.x, tid = threadIdx.x;
    __shared__ float red[4];
    float a0 = sbuf[(b << 9) + tid], a1 = sbuf[(b << 9) + 256 + tid];
    float s = blockReduceSum(a0 + a1, red);
    float s2 = blockReduceSum(a0 * a0 + a1 * a1, red);
    float mean = s * (1.f / 512.f);
    float rs = rsqrtf(s2 * (1.f / 512.f) - mean * mean + EPS);
    out[(b << 9) + tid] = (a0 - mean) * rs * nw[tid] + nb[tid];
    out[(b << 9) + 256 + tid] = (a1 - mean) * rs * nw[tid + 256] + nb[tid + 256];
}

// ============================ host launcher =====================================
extern "C" void kernel_launch(void* const* d_in, const int* in_sizes, int n_in,
                              void* d_out, int out_size, void* d_ws, size_t ws_size,
                              hipStream_t stream)
{
    const float* x    = (const float*)d_in[0];
    const float* kc   = (const float*)d_in[1];
    const float* vc   = (const float*)d_in[2];
    const float* qkvw = (const float*)d_in[4];
    const float* qkvb = (const float*)d_in[5];
    const float* outw = (const float*)d_in[6];
    const float* outb = (const float*)d_in[7];
    const float* w1   = (const float*)d_in[8];
    const float* b1   = (const float*)d_in[9];
    const float* w2   = (const float*)d_in[10];
    const float* b2   = (const float*)d_in[11];
    const float* nw1  = (const float*)d_in[12];
    const float* nb1  = (const float*)d_in[13];
    const float* nw2  = (const float*)d_in[14];
    const float* nb2  = (const float*)d_in[15];
    const int*   posp = (const int*)d_in[16];

    // Occupancy gate for the cooperative path (host queries only, capture-safe).
    int dev = 0, cu = 0, nb = 0;
    hipGetDevice(&dev);
    hipDeviceGetAttribute(&cu, hipDeviceAttributeMultiprocessorCount, dev);
    hipOccupancyMaxActiveBlocksPerMultiprocessor(&nb, (const void*)mega, 256, 0);
    const bool coop_ok = ((long)nb * cu >= 512);

    float* ws = (float*)d_ws;

    if (coop_ok) {
        Params prm;
        prm.x = x; prm.kc = kc; prm.vc = vc;
        prm.qkvw = qkvw; prm.qkvb = qkvb; prm.outw = outw; prm.outb = outb;
        prm.w1 = w1; prm.b1 = b1; prm.w2 = w2; prm.b2 = b2;
        prm.nw1 = nw1; prm.nb1 = nb1; prm.nw2 = nw2; prm.nb2 = nb2;
        prm.posp = posp;
        prm.qkvbuf = ws;                  // 6144
        prm.part   = prm.qkvbuf + 6144;   // 64*8*34 = 17408
        prm.t1     = prm.part + 17408;    // 2048
        prm.m1     = prm.t1 + 2048;       // 8192
        prm.sbuf   = prm.m1 + 8192;       // 2048
        prm.out    = (float*)d_out;
        void* args[] = { &prm };
        hipLaunchCooperativeKernel(reinterpret_cast<const void*>(&mega),
                                   dim3(512), dim3(256), args, 0, stream);
        return;
    }

    // -------- fallback: round-1 multi-kernel path --------
    float* qkvbuf = ws;                   // 6144
    float* part   = qkvbuf + 6144;        // B*H*NCH*34 = 19584
    float* t1     = part + 19584;         // 2048
    float* m1     = t1 + 2048;            // 8192
    float* sbuf   = m1 + 8192;            // 2048
    const size_t kvLayerStride = (size_t)B * H * S * HD;

    for (int l = 0; l < LNUM; ++l) {
        const float* hsrc = (l == 0) ? x : sbuf;
        const int aln = (l > 0) ? 1 : 0;
        const float* pnw = (l > 0) ? (nw2 + (size_t)(l - 1) * 512) : nullptr;
        const float* pnb = (l > 0) ? (nb2 + (size_t)(l - 1) * 512) : nullptr;

        k_qkv<<<1536, 256, 0, stream>>>(hsrc, aln, pnw, pnb,
                                        qkvw + (size_t)l * 1536 * 512,
                                        qkvb + (size_t)l * 1536, qkvbuf);
        k_attn<<<B * H * NCH, 256, 0, stream>>>(kc + (size_t)l * kvLayerStride,
                                                vc + (size_t)l * kvLayerStride,
                                                qkvbuf, part, posp);
        k_outproj<<<B * 32, 256, 0, stream>>>(part,
                                              outw + (size_t)l * 512 * 512,
                                              outb + (size_t)l * 512,
                                              hsrc, aln, pnw, pnb, t1);
        k_mlp1<<<B * 128, 256, 0, stream>>>(t1,
                                            nw1 + (size_t)l * 512, nb1 + (size_t)l * 512,
                                            w1 + (size_t)l * FF * D, b1 + (size_t)l * FF, m1);
        k_mlp2<<<B * 128, 256, 0, stream>>>(m1, t1,
                                            nw1 + (size_t)l * 512, nb1 + (size_t)l * 512,
                                            w2 + (size_t)l * D * FF, b2 + (size_t)l * 512, sbuf);
    }
    k_finalln<<<B, 256, 0, stream>>>(sbuf, nw2 + 23 * 512, nb2 + 23 * 512, (float*)d_out);
}

// Round 4
// 843.070 us; speedup vs baseline: 1.0017x; 1.0017x over previous
//
#include <hip/hip_runtime.h>

// Text2SemanticDecoder decode step. One persistent cooperative kernel
// (512 blocks x 256 thr, 24.6 KB LDS). Hand-rolled split arrive/wait grid
// barrier; all barrier-independent HBM loads (weights, KV chunks) prefetched
// into registers between arrive and wait so spins overlap memory latency.
// Fallback (occupancy gate fails): round-1 multi-kernel path.

#define DEV __device__ __forceinline__

static constexpr int LNUM = 24;
static constexpr int B = 4;
static constexpr int H = 16;
static constexpr int D = 512;
static constexpr int S = 4096;
static constexpr int FF = 2048;
static constexpr int HD = 32;
static constexpr int NCH = 9;        // fallback chunking
static constexpr int NBLK = 512;     // coop grid size
static constexpr float EPS = 1e-5f;
static constexpr float SCALE = 0.17677669529663687f;  // 1/sqrt(32)

DEV float waveReduceSum(float v) {
#pragma unroll
    for (int o = 32; o > 0; o >>= 1) v += __shfl_xor(v, o);
    return v;
}
DEV float waveReduceMax(float v) {
#pragma unroll
    for (int o = 32; o > 0; o >>= 1) v = fmaxf(v, __shfl_xor(v, o));
    return v;
}
DEV float blockReduceSum(float v, volatile float* red) {
    v = waveReduceSum(v);
    __syncthreads();
    if ((threadIdx.x & 63) == 0) red[threadIdx.x >> 6] = v;
    __syncthreads();
    return red[0] + red[1] + red[2] + red[3];
}
DEV float blockReduceMax(float v, volatile float* red) {
    v = waveReduceMax(v);
    __syncthreads();
    if ((threadIdx.x & 63) == 0) red[threadIdx.x >> 6] = v;
    __syncthreads();
    return fmaxf(fmaxf(red[0], red[1]), fmaxf(red[2], red[3]));
}

// ---- split grid barrier: monotonically increasing counter, zeroed per launch ----
DEV void gbar_arrive(unsigned* ctr) {
    __syncthreads();  // all waves' global writes drained (vmcnt0 per wave)
    if (threadIdx.x == 0)
        __hip_atomic_fetch_add(ctr, 1u, __ATOMIC_RELEASE, __HIP_MEMORY_SCOPE_AGENT);
}
DEV void gbar_wait(unsigned* ctr, unsigned target) {
    if (threadIdx.x == 0) {
        while (__hip_atomic_load(ctr, __ATOMIC_RELAXED, __HIP_MEMORY_SCOPE_AGENT) < target)
            __builtin_amdgcn_s_sleep(1);
        __builtin_amdgcn_fence(__ATOMIC_ACQUIRE, "agent");
    }
    __syncthreads();
}

struct Params {
    const float *x, *kc, *vc;
    const float *qkvw, *qkvb, *outw, *outb, *w1, *b1, *w2, *b2;
    const float *nw1, *nb1, *nw2, *nb2;
    const int* posp;
    float *qkvbuf, *part, *t1, *m1, *sbuf, *out;
    unsigned* bar;
};

// LDS (floats), 6160 = 24.6 KB. [0..2047] staged vec; P3: [2048..2175] mh/sh,
// [2176..4223] combined attn; P5: [0..4095] m1 half, [4096..6143] t1 raw;
// [6152..6155] reduce scratch.
__global__ __launch_bounds__(256, 2) void mega(Params p) {
    const int blk = blockIdx.x;   // 0..511
    const int tid = threadIdx.x;  // 0..255
    const int w = tid >> 6;       // wave = batch index for vector phases
    const int lane = tid & 63;
    const int pos = p.posp[0];
    unsigned* ctr = p.bar;
    unsigned nbar = 0;

    __shared__ float SM[6160];
    float* red = SM + 6152;

    const int r1 = (blk << 2) + w;  // qkv row (valid <1536) / w1 row (0..2047)

    // prefetch layer-0 qkv weight row
    float4 wA, wB;
    if (r1 < 1536) {
        const float4* wr4 = (const float4*)(p.qkvw + (size_t)r1 * 512);
        wA = wr4[lane]; wB = wr4[lane + 64];
    }

    for (int l = 0; l < LNUM; ++l) {
        const float* hsrc = (l == 0) ? p.x : p.sbuf;
        const bool aln = (l > 0);
        const float* pnw = p.nw2 + (aln ? (size_t)(l - 1) * 512 : 0);
        const float* pnb = p.nb2 + (aln ? (size_t)(l - 1) * 512 : 0);
        const float* qbL = p.qkvb + (size_t)l * 1536;
        const float* kcL = p.kc + (size_t)l * 8388608;
        const float* vcL = p.vc + (size_t)l * 8388608;
        const float* owL = p.outw + (size_t)l * 512 * 512;
        const float* obL = p.outb + (size_t)l * 512;
        const float* w1L = p.w1 + (size_t)l * 2048 * 512;
        const float* b1L = p.b1 + (size_t)l * 2048;
        const float* w2L = p.w2 + (size_t)l * 512 * 2048;
        const float* b2L = p.b2 + (size_t)l * 512;
        const float* n1w = p.nw1 + (size_t)l * 512;
        const float* n1b = p.nb1 + (size_t)l * 512;

        // ===== Phase 1: stage h (+LN2); qkv GEMV with prefetched row =====
        {
            if (l) gbar_wait(ctr, nbar * NBLK);
            const float4* s4 = (const float4*)hsrc;
            float4 hr0 = s4[tid], hr1 = s4[tid + 256];
            float4* m4 = (float4*)SM;
            m4[tid] = hr0; m4[tid + 256] = hr1;
            __syncthreads();
            float4* h4 = (float4*)(SM + (w << 9));
            float4 aa = h4[lane], bbv = h4[lane + 64];
            float s = aa.x + aa.y + aa.z + aa.w + bbv.x + bbv.y + bbv.z + bbv.w;
            float s2 = aa.x * aa.x + aa.y * aa.y + aa.z * aa.z + aa.w * aa.w
                     + bbv.x * bbv.x + bbv.y * bbv.y + bbv.z * bbv.z + bbv.w * bbv.w;
            s = waveReduceSum(s);
            s2 = waveReduceSum(s2);
            float mean = s * (1.f / 512.f);
            float rs = rsqrtf(s2 * (1.f / 512.f) - mean * mean + EPS);
            if (aln) {
                const float4* gw4 = (const float4*)pnw;
                const float4* gb4 = (const float4*)pnb;
                float4 gw = gw4[lane], gb = gb4[lane];
                aa.x = (aa.x - mean) * rs * gw.x + gb.x;
                aa.y = (aa.y - mean) * rs * gw.y + gb.y;
                aa.z = (aa.z - mean) * rs * gw.z + gb.z;
                aa.w = (aa.w - mean) * rs * gw.w + gb.w;
                h4[lane] = aa;
                gw = gw4[lane + 64]; gb = gb4[lane + 64];
                bbv.x = (bbv.x - mean) * rs * gw.x + gb.x;
                bbv.y = (bbv.y - mean) * rs * gw.y + gb.y;
                bbv.z = (bbv.z - mean) * rs * gw.z + gb.z;
                bbv.w = (bbv.w - mean) * rs * gw.w + gb.w;
                h4[lane + 64] = bbv;
            }
            __syncthreads();
            if (r1 < 1536) {
                float acc[4];
#pragma unroll
                for (int b = 0; b < 4; ++b) {
                    const float4* hb4 = (const float4*)(SM + (b << 9));
                    float4 hA = hb4[lane], hB = hb4[lane + 64];
                    float a = wA.x * hA.x + wA.y * hA.y + wA.z * hA.z + wA.w * hA.w
                            + wB.x * hB.x + wB.y * hB.y + wB.z * hB.z + wB.w * hB.w;
                    acc[b] = waveReduceSum(a);
                }
                if (lane == 0) {
                    float bias = qbL[r1];
                    float sc = (r1 < 512) ? SCALE : 1.f;
#pragma unroll
                    for (int b = 0; b < 4; ++b)
                        p.qkvbuf[b * 1536 + r1] = (acc[b] + bias) * sc;
                }
            }
            gbar_arrive(ctr); ++nbar;
        }

        // ===== Phase 2: attention; K row + V cols prefetched before wait =====
        {
            const int c = blk & 7, bh = blk >> 3;
            const int bb2 = bh >> 4, hh2 = bh & 15;
            const int pp2 = (c << 8) + tid;
            float4 kpre[8];
            {
                const float4* kp = (const float4*)(kcL + ((size_t)bh * 4096 + pp2) * 32);
#pragma unroll
                for (int i = 0; i < 8; ++i) kpre[i] = kp[i];
            }
            float vpre[32];
            {
                const float* vp = vcL + ((size_t)bh * 4096 + (c << 8) + ((tid >> 5) << 5)) * 32 + (tid & 31);
#pragma unroll
                for (int i = 0; i < 32; ++i) vpre[i] = vp[(size_t)i * 32];
            }
            gbar_wait(ctr, nbar * NBLK);
            float* qs = SM;        // 32
            float* es = SM + 32;   // 256
            float* op = SM + 288;  // 8*33
            float* sn = SM + 560;  // 1
            if (tid < 32) qs[tid] = p.qkvbuf[bb2 * 1536 + (hh2 << 5) + tid];
            __syncthreads();
            float sc = 0.f;
#pragma unroll
            for (int i = 0; i < 8; ++i)
                sc += qs[4 * i] * kpre[i].x + qs[4 * i + 1] * kpre[i].y
                    + qs[4 * i + 2] * kpre[i].z + qs[4 * i + 3] * kpre[i].w;
            const bool act = pp2 < pos;
            float score = act ? sc : -1e30f;
            float smax = score, snew = 0.f;
            if (c == 7 && tid == 0) {
                const float* kn = p.qkvbuf + bb2 * 1536 + 512 + (hh2 << 5);
                for (int j = 0; j < 32; ++j) snew += qs[j] * kn[j];
                smax = fmaxf(smax, snew);
            }
            float m = blockReduceMax(smax, red);
            if (tid == 0) sn[0] = (c == 7) ? expf(snew - m) : 0.f;
            float e = act ? expf(score - m) : 0.f;
            es[tid] = e;
            float lsum = blockReduceSum(e, red) + sn[0];
            const int d = tid & 31, g = tid >> 5;
            float acc = 0.f;
#pragma unroll
            for (int i = 0; i < 32; ++i) acc += es[(g << 5) + i] * vpre[i];
            if (g == 0) acc += sn[0] * p.qkvbuf[bb2 * 1536 + 1024 + (hh2 << 5) + d];
            op[g * 33 + d] = acc;
            __syncthreads();
            if (tid < 32) {
                float o = 0.f;
#pragma unroll
                for (int gg = 0; gg < 8; ++gg) o += op[gg * 33 + tid];
                float* pt = p.part + (size_t)((bh << 3) + c) * 34;
                pt[2 + tid] = o;
                if (tid == 0) { pt[0] = m; pt[1] = lsum; }
            }
            gbar_arrive(ctr); ++nbar;
        }

        // ===== Phase 3: combine + out-proj + residual -> t1 (ow row + h prefetched) =====
        {
            float4 oA, oB;
            {
                const float4* wr4 = (const float4*)(owL + (size_t)blk * 512);
                oA = wr4[lane]; oB = wr4[lane + 64];
            }
            const float4* s4 = (const float4*)hsrc;   // stable since layer start
            float4 hr0 = s4[tid], hr1 = s4[tid + 256];
            gbar_wait(ctr, nbar * NBLK);
            float4* m4 = (float4*)SM;
            m4[tid] = hr0; m4[tid + 256] = hr1;
            __syncthreads();
            float4* h4 = (float4*)(SM + (w << 9));
            float4 aa = h4[lane], bbv = h4[lane + 64];
            float s = aa.x + aa.y + aa.z + aa.w + bbv.x + bbv.y + bbv.z + bbv.w;
            float s2 = aa.x * aa.x + aa.y * aa.y + aa.z * aa.z + aa.w * aa.w
                     + bbv.x * bbv.x + bbv.y * bbv.y + bbv.z * bbv.z + bbv.w * bbv.w;
            s = waveReduceSum(s);
            s2 = waveReduceSum(s2);
            float mean = s * (1.f / 512.f);
            float rs = rsqrtf(s2 * (1.f / 512.f) - mean * mean + EPS);
            if (tid < 64) {
                const float* pt = p.part + (size_t)(tid << 3) * 34;
                float mh = -1e30f;
#pragma unroll
                for (int cc = 0; cc < 8; ++cc) mh = fmaxf(mh, pt[cc * 34]);
                float ssum = 0.f;
#pragma unroll
                for (int cc = 0; cc < 8; ++cc) ssum += pt[cc * 34 + 1] * expf(pt[cc * 34] - mh);
                SM[2048 + tid] = mh;
                SM[2112 + tid] = ssum;
            }
            __syncthreads();
#pragma unroll
            for (int k = 0; k < 8; ++k) {
                int idx = tid + (k << 8);
                int b = idx >> 9, e = idx & 511, hh = e >> 5, dd = e & 31;
                int bh = (b << 4) + hh;
                const float* pt = p.part + (size_t)(bh << 3) * 34;
                float mh = SM[2048 + bh];
                float inv = 1.f / SM[2112 + bh];
                float o = 0.f;
#pragma unroll
                for (int cc = 0; cc < 8; ++cc) o += pt[cc * 34 + 2 + dd] * expf(pt[cc * 34] - mh);
                SM[2176 + idx] = o * inv;
            }
            __syncthreads();
            const float4* a4 = (const float4*)(SM + 2176 + (w << 9));
            float4 hA = a4[lane], hB = a4[lane + 64];
            float acc = oA.x * hA.x + oA.y * hA.y + oA.z * hA.z + oA.w * hA.w
                      + oB.x * hB.x + oB.y * hB.y + oB.z * hB.z + oB.w * hB.w;
            acc = waveReduceSum(acc);
            if (lane == 0) {
                float hv = SM[(w << 9) + blk];
                if (aln) hv = (hv - mean) * rs * pnw[blk] + pnb[blk];
                p.t1[(w << 9) + blk] = hv + acc + obL[blk];
            }
            gbar_arrive(ctr); ++nbar;
        }

        // ===== Phase 4: LN1(t1); mlp1 GEMV (w1 row + gammas prefetched) =====
        {
            float4 w1A, w1B, g0, g1, gb0, gb1;
            {
                const float4* wr4 = (const float4*)(w1L + (size_t)r1 * 512);
                w1A = wr4[lane]; w1B = wr4[lane + 64];
                const float4* gw4 = (const float4*)n1w;
                const float4* gbb = (const float4*)n1b;
                g0 = gw4[lane]; g1 = gw4[lane + 64];
                gb0 = gbb[lane]; gb1 = gbb[lane + 64];
            }
            gbar_wait(ctr, nbar * NBLK);
            const float4* t4 = (const float4*)p.t1;
            float4 tr0 = t4[tid], tr1 = t4[tid + 256];
            float4* m4 = (float4*)SM;
            m4[tid] = tr0; m4[tid + 256] = tr1;
            __syncthreads();
            float4* h4 = (float4*)(SM + (w << 9));
            float4 aa = h4[lane], bbv = h4[lane + 64];
            float s = aa.x + aa.y + aa.z + aa.w + bbv.x + bbv.y + bbv.z + bbv.w;
            float s2 = aa.x * aa.x + aa.y * aa.y + aa.z * aa.z + aa.w * aa.w
                     + bbv.x * bbv.x + bbv.y * bbv.y + bbv.z * bbv.z + bbv.w * bbv.w;
            s = waveReduceSum(s);
            s2 = waveReduceSum(s2);
            float mean = s * (1.f / 512.f);
            float rs = rsqrtf(s2 * (1.f / 512.f) - mean * mean + EPS);
            aa.x = (aa.x - mean) * rs * g0.x + gb0.x;
            aa.y = (aa.y - mean) * rs * g0.y + gb0.y;
            aa.z = (aa.z - mean) * rs * g0.z + gb0.z;
            aa.w = (aa.w - mean) * rs * g0.w + gb0.w;
            h4[lane] = aa;
            bbv.x = (bbv.x - mean) * rs * g1.x + gb1.x;
            bbv.y = (bbv.y - mean) * rs * g1.y + gb1.y;
            bbv.z = (bbv.z - mean) * rs * g1.z + gb1.z;
            bbv.w = (bbv.w - mean) * rs * g1.w + gb1.w;
            h4[lane + 64] = bbv;
            __syncthreads();
            float acc[4];
#pragma unroll
            for (int b = 0; b < 4; ++b) {
                const float4* hb4 = (const float4*)(SM + (b << 9));
                float4 hA = hb4[lane], hB = hb4[lane + 64];
                float a = w1A.x * hA.x + w1A.y * hA.y + w1A.z * hA.z + w1A.w * hA.w
                        + w1B.x * hB.x + w1B.y * hB.y + w1B.z * hB.z + w1B.w * hB.w;
                acc[b] = waveReduceSum(a);
            }
            if (lane == 0) {
                float bv = b1L[r1];
#pragma unroll
                for (int b = 0; b < 4; ++b)
                    p.m1[(b << 11) + r1] = fmaxf(acc[b] + bv, 0.f);
            }
            gbar_arrive(ctr); ++nbar;
        }

        // ===== Phase 5: mlp2 GEMV + LN1(t1) residual -> sbuf (w2 row + t1 prefetched) =====
        {
            float4 w2pre[8];
            {
                const float4* wr4 = (const float4*)(w2L + (size_t)blk * 2048);
#pragma unroll
                for (int i = 0; i < 8; ++i) w2pre[i] = wr4[(i << 6) + lane];
            }
            const float4* t4 = (const float4*)p.t1;   // ready since phase-3 barrier
            float4 tr0 = t4[tid], tr1 = t4[tid + 256];
            gbar_wait(ctr, nbar * NBLK);
            float4* tB = (float4*)(SM + 4096);
            tB[tid] = tr0; tB[tid + 256] = tr1;
            __syncthreads();
            const float4* h4 = (const float4*)(SM + 4096 + (w << 9));
            float4 aa = h4[lane], bbv = h4[lane + 64];
            float s = aa.x + aa.y + aa.z + aa.w + bbv.x + bbv.y + bbv.z + bbv.w;
            float s2 = aa.x * aa.x + aa.y * aa.y + aa.z * aa.z + aa.w * aa.w
                     + bbv.x * bbv.x + bbv.y * bbv.y + bbv.z * bbv.z + bbv.w * bbv.w;
            s = waveReduceSum(s);
            s2 = waveReduceSum(s2);
            float mean = s * (1.f / 512.f);
            float rs = rsqrtf(s2 * (1.f / 512.f) - mean * mean + EPS);
            float acc = 0.f;
#pragma unroll
            for (int half = 0; half < 2; ++half) {
                __syncthreads();
#pragma unroll
                for (int i = 0; i < 4; ++i) {
                    int idx = tid + (i << 8);
                    int bb3 = idx >> 8, f = idx & 255;
                    ((float4*)SM)[idx] =
                        ((const float4*)(p.m1 + (bb3 << 11) + (half << 10)))[f];
                }
                __syncthreads();
                const float4* mb4 = (const float4*)SM + (w << 8);
#pragma unroll
                for (int i = 0; i < 4; ++i) {
                    float4 q = w2pre[(half << 2) + i];
                    float4 mm = mb4[(i << 6) + lane];
                    acc += q.x * mm.x + q.y * mm.y + q.z * mm.z + q.w * mm.w;
                }
            }
            acc = waveReduceSum(acc);
            if (lane == 0) {
                float tv = SM[4096 + (w << 9) + blk];
                float hv = (tv - mean) * rs * n1w[blk] + n1b[blk];
                p.sbuf[(w << 9) + blk] = hv + acc + b2L[blk];
            }
            gbar_arrive(ctr); ++nbar;
        }

        // prefetch next layer's qkv weight row (hidden under next wait)
        if (l + 1 < LNUM && r1 < 1536) {
            const float4* wr4 = (const float4*)(p.qkvw + (size_t)(l + 1) * 1536 * 512 + (size_t)r1 * 512);
            wA = wr4[lane]; wB = wr4[lane + 64];
        }
    }

    // ===== Final LN2 (layer-23 params) -> d_out =====
    gbar_wait(ctr, nbar * NBLK);
    if (blk < 4) {
        const int b = blk;
        const float* nw = p.nw2 + 23 * 512;
        const float* nb = p.nb2 + 23 * 512;
        float a0 = p.sbuf[(b << 9) + tid];
        float a1 = p.sbuf[(b << 9) + 256 + tid];
        float s = blockReduceSum(a0 + a1, red);
        float s2 = blockReduceSum(a0 * a0 + a1 * a1, red);
        float mean = s * (1.f / 512.f);
        float rs = rsqrtf(s2 * (1.f / 512.f) - mean * mean + EPS);
        p.out[(b << 9) + tid] = (a0 - mean) * rs * nw[tid] + nb[tid];
        p.out[(b << 9) + 256 + tid] = (a1 - mean) * rs * nw[tid + 256] + nb[tid + 256];
    }
}

// ============================ fallback kernels (round-1, known-correct) ==========
__global__ __launch_bounds__(256) void k_qkv(
    const float* __restrict__ hsrc, int apply_ln,
    const float* __restrict__ nw, const float* __restrict__ nb,
    const float* __restrict__ w, const float* __restrict__ bias,
    float* __restrict__ qkv)
{
    const int lane = threadIdx.x & 63;
    const int wid = (blockIdx.x << 2) + (threadIdx.x >> 6);
    const int b = wid / 1536;
    const int r = wid - b * 1536;
    const float* hb = hsrc + (b << 9);
    const int k0 = lane << 3;
    float4 h0 = *(const float4*)(hb + k0);
    float4 h1 = *(const float4*)(hb + k0 + 4);
    float hv[8] = {h0.x, h0.y, h0.z, h0.w, h1.x, h1.y, h1.z, h1.w};
    if (apply_ln) {
        float s = 0.f, s2 = 0.f;
#pragma unroll
        for (int j = 0; j < 8; ++j) { s += hv[j]; s2 += hv[j] * hv[j]; }
        s = waveReduceSum(s);
        s2 = waveReduceSum(s2);
        float mean = s * (1.f / 512.f);
        float rs = rsqrtf(s2 * (1.f / 512.f) - mean * mean + EPS);
        float4 nw0 = *(const float4*)(nw + k0);
        float4 nw1 = *(const float4*)(nw + k0 + 4);
        float4 nb0 = *(const float4*)(nb + k0);
        float4 nb1 = *(const float4*)(nb + k0 + 4);
        float nwv[8] = {nw0.x, nw0.y, nw0.z, nw0.w, nw1.x, nw1.y, nw1.z, nw1.w};
        float nbv[8] = {nb0.x, nb0.y, nb0.z, nb0.w, nb1.x, nb1.y, nb1.z, nb1.w};
#pragma unroll
        for (int j = 0; j < 8; ++j) hv[j] = (hv[j] - mean) * rs * nwv[j] + nbv[j];
    }
    const float* wr = w + (size_t)r * 512 + k0;
    float4 w0 = *(const float4*)(wr);
    float4 w1 = *(const float4*)(wr + 4);
    float acc = w0.x * hv[0] + w0.y * hv[1] + w0.z * hv[2] + w0.w * hv[3]
              + w1.x * hv[4] + w1.y * hv[5] + w1.z * hv[6] + w1.w * hv[7];
    acc = waveReduceSum(acc);
    if (lane == 0) {
        float v = acc + bias[r];
        if (r < 512) v *= SCALE;
        qkv[b * 1536 + r] = v;
    }
}

__global__ __launch_bounds__(256) void k_attn(
    const float* __restrict__ kc, const float* __restrict__ vc,
    const float* __restrict__ qkv, float* __restrict__ part,
    const int* __restrict__ posp)
{
    const int tid = threadIdx.x;
    const int c = blockIdx.x % NCH;
    const int bh = blockIdx.x / NCH;
    const int b = bh >> 4, h = bh & 15;
    const int pos = posp[0];
    __shared__ float qs[32];
    __shared__ float es[256];
    __shared__ float red[4];
    __shared__ float op[8][33];
    if (tid < 32) qs[tid] = qkv[b * 1536 + h * 32 + tid];
    __syncthreads();
    float score = -1e30f;
    bool act = false;
    if (c < 8) {
        int p = c * 256 + tid;
        act = (p < pos);
        const float4* kp = (const float4*)(kc + ((size_t)bh * S + p) * HD);
        float s = 0.f;
#pragma unroll
        for (int i = 0; i < 8; ++i) {
            float4 kv = kp[i];
            s += qs[4 * i] * kv.x + qs[4 * i + 1] * kv.y + qs[4 * i + 2] * kv.z + qs[4 * i + 3] * kv.w;
        }
        if (act) score = s;
    } else if (tid == 0) {
        act = true;
        const float* kp = qkv + b * 1536 + 512 + h * 32;
        float s = 0.f;
#pragma unroll
        for (int j = 0; j < 32; ++j) s += qs[j] * kp[j];
        score = s;
    }
    float m = blockReduceMax(score, red);
    float e = act ? expf(score - m) : 0.f;
    es[tid] = e;
    float l = blockReduceSum(e, red);
    const int d = tid & 31, g = tid >> 5;
    float acc = 0.f;
    if (c < 8) {
        const float* vp = vc + ((size_t)bh * S + c * 256 + g * 32) * HD + d;
#pragma unroll 8
        for (int i = 0; i < 32; ++i) acc += es[g * 32 + i] * vp[(size_t)i * HD];
    } else if (g == 0) {
        acc = es[0] * qkv[b * 1536 + 1024 + h * 32 + d];
    }
    op[g][d] = acc;
    __syncthreads();
    if (tid < 32) {
        float o = 0.f;
#pragma unroll
        for (int gg = 0; gg < 8; ++gg) o += op[gg][tid];
        float* pp = part + (size_t)(bh * NCH + c) * 34;
        pp[2 + tid] = o;
        if (tid == 0) { pp[0] = m; pp[1] = l; }
    }
}

__global__ __launch_bounds__(256) void k_outproj(
    const float* __restrict__ part,
    const float* __restrict__ ow, const float* __restrict__ ob,
    const float* __restrict__ hsrc, int apply_ln,
    const float* __restrict__ nw, const float* __restrict__ nb,
    float* __restrict__ t1)
{
    const int tid = threadIdx.x;
    const int b = blockIdx.x >> 5;
    const int oc = blockIdx.x & 31;
    __shared__ float attn_s[512];
    __shared__ float hln[512];
    __shared__ float mh[16], sh[16];
    __shared__ float red[4];
    if (tid < 16) {
        const float* pp = part + (size_t)(b * 16 + tid) * NCH * 34;
        float m = -1e30f;
        for (int c = 0; c < NCH; ++c) m = fmaxf(m, pp[c * 34]);
        float ss = 0.f;
        for (int c = 0; c < NCH; ++c) ss += pp[c * 34 + 1] * expf(pp[c * 34] - m);
        mh[tid] = m;
        sh[tid] = ss;
    }
    __syncthreads();
#pragma unroll
    for (int e = tid; e < 512; e += 256) {
        int h = e >> 5, d = e & 31;
        const float* pp = part + (size_t)(b * 16 + h) * NCH * 34;
        float o = 0.f;
        for (int c = 0; c < NCH; ++c) o += pp[c * 34 + 2 + d] * expf(pp[c * 34] - mh[h]);
        attn_s[e] = o / sh[h];
    }
    float a0 = hsrc[(b << 9) + tid], a1 = hsrc[(b << 9) + 256 + tid];
    if (apply_ln) {
        float s = blockReduceSum(a0 + a1, red);
        float s2 = blockReduceSum(a0 * a0 + a1 * a1, red);
        float mean = s * (1.f / 512.f);
        float rs = rsqrtf(s2 * (1.f / 512.f) - mean * mean + EPS);
        hln[tid] = (a0 - mean) * rs * nw[tid] + nb[tid];
        hln[tid + 256] = (a1 - mean) * rs * nw[tid + 256] + nb[tid + 256];
    } else {
        hln[tid] = a0;
        hln[tid + 256] = a1;
    }
    __syncthreads();
    const int w = tid >> 6, lane = tid & 63, k0 = lane << 3;
#pragma unroll
    for (int oi = 0; oi < 4; ++oi) {
        int dd = (oc << 4) + (w << 2) + oi;
        const float4* wp = (const float4*)(ow + (size_t)dd * 512 + k0);
        float4 w0 = wp[0], w1 = wp[1];
        float acc = w0.x * attn_s[k0] + w0.y * attn_s[k0 + 1] + w0.z * attn_s[k0 + 2] + w0.w * attn_s[k0 + 3]
                  + w1.x * attn_s[k0 + 4] + w1.y * attn_s[k0 + 5] + w1.z * attn_s[k0 + 6] + w1.w * attn_s[k0 + 7];
        acc = waveReduceSum(acc);
        if (lane == 0) t1[(b << 9) + dd] = hln[dd] + acc + ob[dd];
    }
}

__global__ __launch_bounds__(256) void k_mlp1(
    const float* __restrict__ t1,
    const float* __restrict__ nw, const float* __restrict__ nb,
    const float* __restrict__ w1, const float* __restrict__ b1,
    float* __restrict__ m1)
{
    const int tid = threadIdx.x;
    const int b = blockIdx.x >> 7;
    const int oc = blockIdx.x & 127;
    __shared__ float hln[512];
    __shared__ float red[4];
    float a0 = t1[(b << 9) + tid], a1 = t1[(b << 9) + 256 + tid];
    float s = blockReduceSum(a0 + a1, red);
    float s2 = blockReduceSum(a0 * a0 + a1 * a1, red);
    float mean = s * (1.f / 512.f);
    float rs = rsqrtf(s2 * (1.f / 512.f) - mean * mean + EPS);
    hln[tid] = (a0 - mean) * rs * nw[tid] + nb[tid];
    hln[tid + 256] = (a1 - mean) * rs * nw[tid + 256] + nb[tid + 256];
    __syncthreads();
    const int w = tid >> 6, lane = tid & 63, k0 = lane << 3;
#pragma unroll
    for (int oi = 0; oi < 4; ++oi) {
        int r = (oc << 4) + (w << 2) + oi;
        const float4* wp = (const float4*)(w1 + (size_t)r * 512 + k0);
        float4 w0 = wp[0], w1v = wp[1];
        float acc = w0.x * hln[k0] + w0.y * hln[k0 + 1] + w0.z * hln[k0 + 2] + w0.w * hln[k0 + 3]
                  + w1v.x * hln[k0 + 4] + w1v.y * hln[k0 + 5] + w1v.z * hln[k0 + 6] + w1v.w * hln[k0 + 7];
        acc = waveReduceSum(acc);
        if (lane == 0) m1[(b << 11) + r] = fmaxf(acc + b1[r], 0.f);
    }
}

__global__ __launch_bounds__(256) void k_mlp2(
    const float* __restrict__ m1, const float* __restrict__ t1,
    const float* __restrict__ nw, const float* __restrict__ nb,
    const float* __restrict__ w2, const float* __restrict__ b2,
    float* __restrict__ sout)
{
    const int tid = threadIdx.x;
    const int b = blockIdx.x >> 7;
    const int oc = blockIdx.x & 127;
    __shared__ float ms[2048];
    __shared__ float red[4];
#pragma unroll
    for (int i = 0; i < 8; ++i) ms[tid + (i << 8)] = m1[(b << 11) + tid + (i << 8)];
    float a0 = t1[(b << 9) + tid], a1 = t1[(b << 9) + 256 + tid];
    float s = blockReduceSum(a0 + a1, red);
    float s2 = blockReduceSum(a0 * a0 + a1 * a1, red);
    float mean = s * (1.f / 512.f);
    float rs = rsqrtf(s2 * (1.f / 512.f) - mean * mean + EPS);
    const int w = tid >> 6, lane = tid & 63;
    const int dd = (oc << 2) + w;
    const float4* wp = (const float4*)(w2 + (size_t)dd * 2048);
    float acc = 0.f;
#pragma unroll
    for (int i = 0; i < 8; ++i) {
        int idx = (i << 6) + lane;
        float4 q = wp[idx];
        int k = idx << 2;
        acc += q.x * ms[k] + q.y * ms[k + 1] + q.z * ms[k + 2] + q.w * ms[k + 3];
    }
    acc = waveReduceSum(acc);
    if (lane == 0) {
        float td = t1[(b << 9) + dd];
        float hd = (td - mean) * rs * nw[dd] + nb[dd];
        sout[(b << 9) + dd] = hd + acc + b2[dd];
    }
}

__global__ __launch_bounds__(256) void k_finalln(
    const float* __restrict__ sbuf,
    const float* __restrict__ nw, const float* __restrict__ nb,
    float* __restrict__ out)
{
    const int b = blockIdx.x, tid = threadIdx.x;
    __shared__ float red[4];
    float a0 = sbuf[(b << 9) + tid], a1 = sbuf[(b << 9) + 256 + tid];
    float s = blockReduceSum(a0 + a1, red);
    float s2 = blockReduceSum(a0 * a0 + a1 * a1, red);
    float mean = s * (1.f / 512.f);
    float rs = rsqrtf(s2 * (1.f / 512.f) - mean * mean + EPS);
    out[(b << 9) + tid] = (a0 - mean) * rs * nw[tid] + nb[tid];
    out[(b << 9) + 256 + tid] = (a1 - mean) * rs * nw[tid + 256] + nb[tid + 256];
}

// ============================ host launcher =====================================
extern "C" void kernel_launch(void* const* d_in, const int* in_sizes, int n_in,
                              void* d_out, int out_size, void* d_ws, size_t ws_size,
                              hipStream_t stream)
{
    const float* x    = (const float*)d_in[0];
    const float* kc   = (const float*)d_in[1];
    const float* vc   = (const float*)d_in[2];
    const float* qkvw = (const float*)d_in[4];
    const float* qkvb = (const float*)d_in[5];
    const float* outw = (const float*)d_in[6];
    const float* outb = (const float*)d_in[7];
    const float* w1   = (const float*)d_in[8];
    const float* b1   = (const float*)d_in[9];
    const float* w2   = (const float*)d_in[10];
    const float* b2   = (const float*)d_in[11];
    const float* nw1  = (const float*)d_in[12];
    const float* nb1  = (const float*)d_in[13];
    const float* nw2  = (const float*)d_in[14];
    const float* nb2  = (const float*)d_in[15];
    const int*   posp = (const int*)d_in[16];

    int dev = 0, cu = 0, nb = 0;
    hipGetDevice(&dev);
    hipDeviceGetAttribute(&cu, hipDeviceAttributeMultiprocessorCount, dev);
    hipOccupancyMaxActiveBlocksPerMultiprocessor(&nb, (const void*)mega, 256, 0);
    const bool coop_ok = ((long)nb * cu >= NBLK);

    float* ws = (float*)d_ws;

    if (coop_ok) {
        Params prm;
        prm.x = x; prm.kc = kc; prm.vc = vc;
        prm.qkvw = qkvw; prm.qkvb = qkvb; prm.outw = outw; prm.outb = outb;
        prm.w1 = w1; prm.b1 = b1; prm.w2 = w2; prm.b2 = b2;
        prm.nw1 = nw1; prm.nb1 = nb1; prm.nw2 = nw2; prm.nb2 = nb2;
        prm.posp = posp;
        prm.qkvbuf = ws;                  // 6144
        prm.part   = prm.qkvbuf + 6144;   // 64*8*34 = 17408
        prm.t1     = prm.part + 17408;    // 2048
        prm.m1     = prm.t1 + 2048;       // 8192
        prm.sbuf   = prm.m1 + 8192;       // 2048  (ends at 35840)
        prm.out    = (float*)d_out;
        prm.bar    = (unsigned*)(ws + 35840);
        hipMemsetAsync(prm.bar, 0, 64, stream);   // capture-safe reset each call
        void* args[] = { &prm };
        hipLaunchCooperativeKernel(reinterpret_cast<const void*>(&mega),
                                   dim3(NBLK), dim3(256), args, 0, stream);
        return;
    }

    // -------- fallback: round-1 multi-kernel path --------
    float* qkvbuf = ws;
    float* part   = qkvbuf + 6144;
    float* t1     = part + 19584;
    float* m1     = t1 + 2048;
    float* sbuf   = m1 + 8192;
    const size_t kvLayerStride = (size_t)B * H * S * HD;

    for (int l = 0; l < LNUM; ++l) {
        const float* hsrc = (l == 0) ? x : sbuf;
        const int aln = (l > 0) ? 1 : 0;
        const float* pnw = (l > 0) ? (nw2 + (size_t)(l - 1) * 512) : nullptr;
        const float* pnb = (l > 0) ? (nb2 + (size_t)(l - 1) * 512) : nullptr;

        k_qkv<<<1536, 256, 0, stream>>>(hsrc, aln, pnw, pnb,
                                        qkvw + (size_t)l * 1536 * 512,
                                        qkvb + (size_t)l * 1536, qkvbuf);
        k_attn<<<B * H * NCH, 256, 0, stream>>>(kc + (size_t)l * kvLayerStride,
                                                vc + (size_t)l * kvLayerStride,
                                                qkvbuf, part, posp);
        k_outproj<<<B * 32, 256, 0, stream>>>(part,
                                              outw + (size_t)l * 512 * 512,
                                              outb + (size_t)l * 512,
                                              hsrc, aln, pnw, pnb, t1);
        k_mlp1<<<B * 128, 256, 0, stream>>>(t1,
                                            nw1 + (size_t)l * 512, nb1 + (size_t)l * 512,
                                            w1 + (size_t)l * FF * D, b1 + (size_t)l * FF, m1);
        k_mlp2<<<B * 128, 256, 0, stream>>>(m1, t1,
                                            nw1 + (size_t)l * 512, nb1 + (size_t)l * 512,
                                            w2 + (size_t)l * D * FF, b2 + (size_t)l * 512, sbuf);
    }
    k_finalln<<<B, 256, 0, stream>>>(sbuf, nw2 + 23 * 512, nb2 + 23 * 512, (float*)d_out);
}